// Round 1
// 311.703 us; speedup vs baseline: 1.0334x; 1.0334x over previous
//
#include <hip/hip_runtime.h>

#define NN 100000
#define NE 640000
#define IND 128
#define HD 256
#define NC 40
#define MT 64      // nodes per block in MLP
#define HPAD 264   // h_s row stride (bf16 elems)
#define LPAD 52    // l_s row stride (f32)

typedef unsigned short u16;
typedef unsigned int u32;
typedef __attribute__((ext_vector_type(8))) short bf16x8;
typedef __attribute__((ext_vector_type(4))) float f32x4;

__device__ __forceinline__ float bf2f(u16 u) {
    union { u32 i; float f; } c; c.i = ((u32)u) << 16; return c.f;
}
__device__ __forceinline__ u16 f2bf(float f) {
    union { float f; u32 i; } c; c.f = f;
    u32 i = c.i;
    return (u16)((i + 0x7FFFu + ((i >> 16) & 1u)) >> 16); // RNE
}

// P1: deg count + feats->bf16 + W1/W2 fragment packing (deg pre-zeroed by memset)
__global__ __launch_bounds__(256) void prep_k(
    const int* __restrict__ dst, int* __restrict__ deg,
    const float2* __restrict__ feats, u32* __restrict__ xF,
    const float* __restrict__ W1, const float* __restrict__ W2,
    u16* __restrict__ pw1, u16* __restrict__ pw2)
{
    const int gtid = blockIdx.x * 256 + threadIdx.x, gsz = gridDim.x * 256;
    if (gtid < 4096) {                       // W1 [128x256] -> [ct16][ks4][lane64][j8]
        int lane = gtid & 63, fid = gtid >> 6;
        int ks = fid & 3, ct = fid >> 2;
        int quad = lane >> 4, m = lane & 15;
        int n = ct * 16 + m;
        u16* o = pw1 + (size_t)gtid * 8;
        #pragma unroll
        for (int j = 0; j < 8; j++) o[j] = f2bf(W1[(ks * 32 + quad * 8 + j) * HD + n]);
    } else if (gtid < 4096 + 1536) {         // W2 [256x40] -> [ct3][ks8][lane64][j8] pad 48
        int idx = gtid - 4096;
        int lane = idx & 63, fid = idx >> 6;
        int ks = fid & 7, ct = fid >> 3;
        int quad = lane >> 4, m = lane & 15;
        int n = ct * 16 + m;
        u16* o = pw2 + (size_t)idx * 8;
        #pragma unroll
        for (int j = 0; j < 8; j++)
            o[j] = (n < NC) ? f2bf(W2[(ks * 32 + quad * 8 + j) * NC + n]) : (u16)0;
    }
    for (int i = gtid; i < NN * (IND / 2); i += gsz) {
        float2 v = feats[i];
        xF[i] = (u32)f2bf(v.x) | ((u32)f2bf(v.y) << 16);
    }
    for (int e = gtid; e < NE; e += gsz) atomicAdd(&deg[dst[e]], 1);
}

// P2: CSR segment allocation without a global scan: wave-scan + one atomicAdd/wave.
__global__ __launch_bounds__(256) void alloc_k(
    const int* __restrict__ deg, int* __restrict__ gtotal,
    int2* __restrict__ rb, int* __restrict__ cursor, float* __restrict__ norm)
{
    const int gtid = blockIdx.x * 256 + threadIdx.x;
    const int lane = threadIdx.x & 63;
    const int i0 = gtid * 4;
    int d[4]; int own = 0;
    #pragma unroll
    for (int j = 0; j < 4; j++) {
        d[j] = (i0 + j < NN) ? deg[i0 + j] : 0;
        own += d[j];
    }
    int incl = own;
    #pragma unroll
    for (int off = 1; off < 64; off <<= 1) {
        int v = __shfl_up(incl, off);
        if (lane >= off) incl += v;
    }
    int base = 0;
    if (lane == 63) base = atomicAdd(gtotal, incl);
    base = __shfl(base, 63);
    int run = base + incl - own;
    #pragma unroll
    for (int j = 0; j < 4; j++) {
        int i = i0 + j;
        if (i < NN) {
            cursor[i] = run;
            rb[i] = make_int2(run, run + d[j]);
            norm[i] = rsqrtf(fmaxf((float)d[j], 1.0f));
            run += d[j];
        }
    }
}

// P3: CSR fill: cv = {src, bits(norm[src]*norm[dst])}
__global__ void fill_k(const int* __restrict__ src, const int* __restrict__ dst,
                       const float* __restrict__ norm, int* __restrict__ cursor,
                       int2* __restrict__ cv, int E) {
    int e = blockIdx.x * 256 + threadIdx.x;
    if (e >= E) return;
    int s = src[e], d = dst[e];
    int pos = atomicAdd(&cursor[d], 1);
    cv[pos] = make_int2(s, __float_as_int(norm[s] * norm[d]));
}

// P4/P5: gather-SpMM v2 — ONE ROW PER WAVE.
// 64 lanes x 1 dword = full 256B row per gather instruction.
// All edge metadata (beg/end, cv entries, tail mask, row base address) is
// forced onto the scalar pipe via readfirstlane: per edge the VALU does only
// 2 unpacks + 2 fmas; address math is SGPR-base + loop-invariant lane offset.
// Accumulation order per feature is identical to v1 (bitwise-same output).
// LAST: ys = 0.25*(x0 + x1 + x + a), pre-scaled bf16 for the MLP.
template <int LAST>
__global__ __launch_bounds__(256) void spmm_k(
    const u32* __restrict__ x, u32* __restrict__ xnext,
    const u32* __restrict__ x0, const u32* __restrict__ x1,
    const int2* __restrict__ rb, const int2* __restrict__ cv)
{
    int row = (blockIdx.x * 256 + threadIdx.x) >> 6;
    row = __builtin_amdgcn_readfirstlane(row);          // wave-uniform
    const int lane = threadIdx.x & 63;
    if (row >= NN) return;

    const int2 be = rb[row];                            // uniform addr (broadcast)
    const int beg = __builtin_amdgcn_readfirstlane(be.x);
    const int end = __builtin_amdgcn_readfirstlane(be.y);

    float a0 = 0.f, a1 = 0.f;
    for (int b = beg; b < end; b += 8) {
        int  sN[8];
        float wN[8];
        #pragma unroll
        for (int j = 0; j < 8; j++) {
            const int ee = b + j;
            const int2 c = cv[(ee < NE) ? ee : (NE - 1)];   // uniform load
            sN[j] = __builtin_amdgcn_readfirstlane(c.x);
            u32 wb = (u32)__builtin_amdgcn_readfirstlane(c.y);
            if (ee >= end) wb = 0u;                          // scalar select -> w = 0
            wN[j] = __int_as_float((int)wb);
        }
        u32 u[8];
        #pragma unroll
        for (int j = 0; j < 8; j++) {
            const u32* rp = x + ((size_t)sN[j] << 6);        // SGPR base per edge
            u[j] = rp[lane];                                 // coalesced 256B row
        }
        #pragma unroll
        for (int j = 0; j < 8; j++) {
            a0 = fmaf(bf2f((u16)(u[j] & 0xFFFFu)), wN[j], a0);
            a1 = fmaf(bf2f((u16)(u[j] >> 16)),     wN[j], a1);
        }
    }

    const size_t ri = (size_t)row * 64 + lane;
    u32 o;
    if (!LAST) {
        o = (u32)f2bf(a0) | ((u32)f2bf(a1) << 16);
    } else {
        const u32 v0 = x0[ri];
        const u32 v1 = x1[ri];
        const u32 v2 = x[ri];
        const float s0 = bf2f((u16)(v0 & 0xFFFFu)) + bf2f((u16)(v1 & 0xFFFFu))
                       + bf2f((u16)(v2 & 0xFFFFu)) + a0;
        const float s1 = bf2f((u16)(v0 >> 16)) + bf2f((u16)(v1 >> 16))
                       + bf2f((u16)(v2 >> 16)) + a1;
        o = (u32)f2bf(s0 * 0.25f) | ((u32)f2bf(s1 * 0.25f) << 16);
    }
    xnext[ri] = o;
}

// P6: MFMA MLP (round-8 structure): 64 nodes/block, 4 waves x 16-node tiles.
__global__ __launch_bounds__(256) void mlp_mfma_k(
    const u16* __restrict__ ys, const u16* __restrict__ pw1,
    const float* __restrict__ B1, const u16* __restrict__ pw2,
    const float* __restrict__ B2, float* __restrict__ out, int N)
{
    __shared__ u16 h_s[MT * HPAD];
    __shared__ float l_s[MT * LPAD];
    const int t = threadIdx.x;
    const int w = t >> 6, lane = t & 63;
    const int quad = lane >> 4, m = lane & 15;
    const int node0 = blockIdx.x * MT;

    int nodeA = node0 + w * 16 + m;
    if (nodeA > N - 1) nodeA = N - 1;
    bf16x8 av[4];
    #pragma unroll
    for (int ks = 0; ks < 4; ks++)
        av[ks] = *(const bf16x8*)(ys + (size_t)nodeA * IND + ks * 32 + quad * 8);

    #pragma unroll 4
    for (int ct = 0; ct < 16; ct++) {
        f32x4 acc = { 0.f, 0.f, 0.f, 0.f };
        #pragma unroll
        for (int ks = 0; ks < 4; ks++) {
            const bf16x8 b = *(const bf16x8*)(pw1 + (size_t)((ct * 4 + ks) * 64 + lane) * 8);
            acc = __builtin_amdgcn_mfma_f32_16x16x32_bf16(av[ks], b, acc, 0, 0, 0);
        }
        const float b1c = B1[ct * 16 + m];
        #pragma unroll
        for (int r = 0; r < 4; r++) {
            const float hv = fmaxf(acc[r] + b1c, 0.0f);
            h_s[(w * 16 + quad * 4 + r) * HPAD + ct * 16 + m] = f2bf(hv);
        }
    }

    f32x4 acc2[3];
    #pragma unroll
    for (int ct = 0; ct < 3; ct++) acc2[ct] = (f32x4){ 0.f, 0.f, 0.f, 0.f };
    #pragma unroll
    for (int ks = 0; ks < 8; ks++) {
        const bf16x8 a = *(const bf16x8*)&h_s[(w * 16 + m) * HPAD + ks * 32 + quad * 8];
        #pragma unroll
        for (int ct = 0; ct < 3; ct++) {
            const bf16x8 b = *(const bf16x8*)(pw2 + (size_t)((ct * 8 + ks) * 64 + lane) * 8);
            acc2[ct] = __builtin_amdgcn_mfma_f32_16x16x32_bf16(a, b, acc2[ct], 0, 0, 0);
        }
    }
    #pragma unroll
    for (int ct = 0; ct < 3; ct++) {
        const int cg = ct * 16 + m;
        const float b2c = (cg < NC) ? B2[cg] : 0.0f;
        #pragma unroll
        for (int r = 0; r < 4; r++)
            l_s[(w * 16 + quad * 4 + r) * LPAD + cg] = acc2[ct][r] + b2c;
    }
    __syncthreads();

    if (t < MT) {
        const int node = node0 + t;
        if (node < N) {
            const float* ln = &l_s[t * LPAD];
            float mx = -1e30f;
            #pragma unroll
            for (int c = 0; c < NC; c++) mx = fmaxf(mx, ln[c]);
            float s = 0.0f;
            #pragma unroll
            for (int c = 0; c < NC; c++) s += __expf(ln[c] - mx);
            const float lse = mx + __logf(s);
            float4* o = (float4*)(out + (size_t)node * NC);
            #pragma unroll
            for (int c4 = 0; c4 < NC / 4; c4++) {
                float4 v;
                v.x = ln[c4 * 4 + 0] - lse;
                v.y = ln[c4 * 4 + 1] - lse;
                v.z = ln[c4 * 4 + 2] - lse;
                v.w = ln[c4 * 4 + 3] - lse;
                o[c4] = v;
            }
        }
    }
}

extern "C" void kernel_launch(void* const* d_in, const int* in_sizes, int n_in,
                              void* d_out, int out_size, void* d_ws, size_t ws_size,
                              hipStream_t stream) {
    const float* feats = (const float*)d_in[0];
    const int* src = (const int*)d_in[1];
    const int* dst = (const int*)d_in[2];
    const float* W1 = (const float*)d_in[3];
    const float* B1 = (const float*)d_in[4];
    const float* W2 = (const float*)d_in[5];
    const float* B2 = (const float*)d_in[6];
    float* out = (float*)d_out;

    char* base = (char*)d_ws;
    size_t off = 0;
    auto alloc = [&](size_t bytes) -> void* {
        void* p = base + off;
        off += (bytes + 255) & ~(size_t)255;
        return p;
    };
    int*   deg    = (int*)  alloc((size_t)NN * 4);
    int*   gtotal = (int*)  alloc(256);          // contiguous after deg; zeroed together
    float* norm   = (float*)alloc((size_t)NN * 4);
    int*   cursor = (int*)  alloc((size_t)NN * 4);
    int2*  rb     = (int2*) alloc((size_t)NN * 8);
    int2*  cv     = (int2*) alloc((size_t)NE * 8);
    u16*   pw1    = (u16*)  alloc((size_t)16 * 4 * 64 * 8 * 2);
    u16*   pw2    = (u16*)  alloc((size_t)3 * 8 * 64 * 8 * 2);
    u32*   xF     = (u32*)  alloc((size_t)NN * (IND / 2) * 4);
    u32*   xA     = (u32*)  alloc((size_t)NN * (IND / 2) * 4);
    u32*   xB     = (u32*)  alloc((size_t)NN * (IND / 2) * 4);
    u32*   ys     = (u32*)  alloc((size_t)NN * (IND / 2) * 4);

    hipMemsetAsync(deg, 0, (((size_t)NN * 4 + 255) & ~(size_t)255) + 256, stream);

    prep_k<<<2048, 256, 0, stream>>>(dst, deg, (const float2*)feats, xF, W1, W2, pw1, pw2);
    alloc_k<<<(NN + 1023) / 1024, 256, 0, stream>>>(deg, gtotal, rb, cursor, norm);
    fill_k<<<(NE + 255) / 256, 256, 0, stream>>>(src, dst, norm, cursor, cv, NE);

    // one wave per row: NN waves = NN*64 threads
    const int sgrid = (NN * 64 + 255) / 256;
    spmm_k<0><<<sgrid, 256, 0, stream>>>(xF, xA, nullptr, nullptr, rb, cv);
    spmm_k<0><<<sgrid, 256, 0, stream>>>(xA, xB, nullptr, nullptr, rb, cv);
    spmm_k<1><<<sgrid, 256, 0, stream>>>(xB, ys, xF, xA, rb, cv);

    const int mgrid = (NN + MT - 1) / MT;
    mlp_mfma_k<<<mgrid, 256, 0, stream>>>((const u16*)ys, pw1, B1, pw2, B2, out, NN);
}